// Round 14
// baseline (846.943 us; speedup 1.0000x reference)
//
#include <hip/hip_runtime.h>
#include <stdint.h>

typedef unsigned short u16;
typedef short bf16x8 __attribute__((ext_vector_type(8)));
typedef float f32x4 __attribute__((ext_vector_type(4)));

#define NTOK 4096
#define CDIM 512
#define NHEAD 8
#define LAYERS 8
#define MLPD 2048
#define QKVD 1536

__device__ __forceinline__ u16 f2bf(float f){
  union { float f; unsigned u; } c; c.f = f;
  return (u16)((c.u + 0x7FFFu + ((c.u >> 16) & 1u)) >> 16);
}

__device__ __forceinline__ unsigned pack2(float a, float b){
  return (unsigned)f2bf(a) | ((unsigned)f2bf(b) << 16);
}

__device__ __forceinline__ void llds16(const void* g, void* l){
  __builtin_amdgcn_global_load_lds((const __attribute__((address_space(1))) void*)g,
                                   (__attribute__((address_space(3))) void*)l, 16, 0, 0);
}

template<int N> __device__ __forceinline__ void wait_vmcnt(){
  if constexpr (N == 0) asm volatile("s_waitcnt vmcnt(0)" ::: "memory");
  else if constexpr (N == 2) asm volatile("s_waitcnt vmcnt(2)" ::: "memory");
  else if constexpr (N == 4) asm volatile("s_waitcnt vmcnt(4)" ::: "memory");
  else static_assert(N == 0 || N == 2 || N == 4, "unsupported vmcnt");
}

// ------- merged prologue: weight transpose+convert (tiled bf16) + token embed ----------
// Wt layout: [n/64][k/64][64][64]. blocks 0..6143 transpose, 6144..6151 w_out (guarded),
// 6152..10247 embed (one token each). 10248 blocks.
__global__ void kt_prologue(const float* __restrict__ wqkv, const float* __restrict__ wo,
                            const float* __restrict__ wm1, const float* __restrict__ wm2,
                            const float* __restrict__ wout,
                            u16* __restrict__ qkvT, u16* __restrict__ oT,
                            u16* __restrict__ m1T, u16* __restrict__ m2T,
                            u16* __restrict__ outT,
                            const float* __restrict__ feats, const int* __restrict__ coords,
                            const float* __restrict__ ex, const float* __restrict__ ey,
                            const float* __restrict__ ez, const float* __restrict__ w_in,
                            const float* __restrict__ b_in, float* __restrict__ h){
  __shared__ float tile[64][65];
  __shared__ float fs[8];
  __shared__ int ccx[3];
  int bid = blockIdx.x;
  int t = threadIdx.x;

  if (bid >= 6152){           // ---- embed segment ----
    int n = bid - 6152;
    if (t < 8) fs[t] = feats[n * 8 + t];
    if (t == 8) { ccx[0] = coords[n*4+1]; ccx[1] = coords[n*4+2]; ccx[2] = coords[n*4+3]; }
    __syncthreads();
    for (int c = t; c < CDIM; c += 256){
      float acc = b_in[c];
      #pragma unroll
      for (int i = 0; i < 8; i++) acc += fs[i] * w_in[i * CDIM + c];
      float pe;
      if (c < 170)      pe = ex[ccx[0] * 170 + c];
      else if (c < 340) pe = ey[ccx[1] * 170 + (c - 170)];
      else              pe = ez[ccx[2] * 172 + (c - 340)];
      h[(size_t)n * CDIM + c] = acc + pe;
    }
    return;
  }

  const float* W; u16* Wt; int K, N, k0, n0; bool guard = false;
  if (bid < 1536){            // qkv: 24 n-tiles x 8 k-tiles per layer
    int l = bid / 192, r = bid % 192;
    W = wqkv + (size_t)l * 512 * 1536; Wt = qkvT + (size_t)l * 512 * 1536;
    K = 512; N = 1536; n0 = (r % 24) * 64; k0 = (r / 24) * 64;
  } else if (bid < 2048){     // o: 8 x 8
    int b = bid - 1536; int l = b / 64, r = b % 64;
    W = wo + (size_t)l * 512 * 512; Wt = oT + (size_t)l * 512 * 512;
    K = 512; N = 512; n0 = (r % 8) * 64; k0 = (r / 8) * 64;
  } else if (bid < 4096){     // m1: 32 x 8
    int b = bid - 2048; int l = b / 256, r = b % 256;
    W = wm1 + (size_t)l * 512 * 2048; Wt = m1T + (size_t)l * 512 * 2048;
    K = 512; N = 2048; n0 = (r % 32) * 64; k0 = (r / 32) * 64;
  } else if (bid < 6144){     // m2: 8 x 32
    int b = bid - 4096; int l = b / 256, r = b % 256;
    W = wm2 + (size_t)l * 2048 * 512; Wt = m2T + (size_t)l * 2048 * 512;
    K = 2048; N = 512; n0 = (r % 8) * 64; k0 = (r / 8) * 64;
  } else {                    // w_out: 1 n-tile (56 guarded, pad 64) x 8 k-tiles
    int r = bid - 6144;
    W = wout; Wt = outT;
    K = 512; N = 56; n0 = 0; k0 = r * 64;
    guard = true;
  }
  int kr = t >> 4, cc = (t & 15) << 2;
  if (guard){
    #pragma unroll
    for (int j = 0; j < 4; j++)
      #pragma unroll
      for (int i = 0; i < 4; i++){
        int col = n0 + cc + i;
        tile[kr + j * 16][cc + i] = (col < N) ? W[(size_t)(k0 + kr + j * 16) * N + col] : 0.f;
      }
  } else {
    #pragma unroll
    for (int j = 0; j < 4; j++){
      float4 v = *(const float4*)&W[(size_t)(k0 + kr + j * 16) * N + n0 + cc];
      tile[kr + j * 16][cc + 0] = v.x;
      tile[kr + j * 16][cc + 1] = v.y;
      tile[kr + j * 16][cc + 2] = v.z;
      tile[kr + j * 16][cc + 3] = v.w;
    }
  }
  __syncthreads();
  size_t tbase = ((size_t)(n0 >> 6) * (K >> 6) + (k0 >> 6)) << 12;
  int nr = t >> 3, kc = (t & 7) << 3;
  #pragma unroll
  for (int s = 0; s < 2; s++){
    int n = nr + s * 32;
    uint4 p;
    p.x = (unsigned)f2bf(tile[kc + 0][n]) | ((unsigned)f2bf(tile[kc + 1][n]) << 16);
    p.y = (unsigned)f2bf(tile[kc + 2][n]) | ((unsigned)f2bf(tile[kc + 3][n]) << 16);
    p.z = (unsigned)f2bf(tile[kc + 4][n]) | ((unsigned)f2bf(tile[kc + 5][n]) << 16);
    p.w = (unsigned)f2bf(tile[kc + 6][n]) | ((unsigned)f2bf(tile[kc + 7][n]) << 16);
    *(uint4*)&Wt[tbase + (size_t)n * 64 + kc] = p;
  }
}

// ---------------- LayerNorm: fp32 h -> bf16 out ----------------
__global__ void kt_ln(const float* __restrict__ h, const float* __restrict__ g,
                      const float* __restrict__ b, u16* __restrict__ out, float eps){
  int wave = threadIdx.x >> 6, lane = threadIdx.x & 63;
  int row = blockIdx.x * 4 + wave;
  const float* hr = h + (size_t)row * CDIM + lane * 8;
  float4 v0 = *(const float4*)hr, v1 = *(const float4*)(hr + 4);
  float x[8] = {v0.x, v0.y, v0.z, v0.w, v1.x, v1.y, v1.z, v1.w};
  float s = 0.f, q = 0.f;
  #pragma unroll
  for (int i = 0; i < 8; i++){ s += x[i]; q += x[i] * x[i]; }
  #pragma unroll
  for (int off = 32; off; off >>= 1){ s += __shfl_xor(s, off); q += __shfl_xor(q, off); }
  float mean = s * (1.0f / CDIM);
  float var  = q * (1.0f / CDIM) - mean * mean;
  float rr = rsqrtf(var + eps);
  int cb = lane * 8;
  u16 u[8];
  #pragma unroll
  for (int i = 0; i < 8; i++)
    u[i] = f2bf((x[i] - mean) * rr * g[cb + i] + b[cb + i]);
  uint4 pk;
  pk.x = (unsigned)u[0] | ((unsigned)u[1] << 16);
  pk.y = (unsigned)u[2] | ((unsigned)u[3] << 16);
  pk.z = (unsigned)u[4] | ((unsigned)u[5] << 16);
  pk.w = (unsigned)u[6] | ((unsigned)u[7] << 16);
  *(uint4*)&out[(size_t)row * CDIM + cb] = pk;
}

// ---------------- bf16 GEMM: C[M=4096][N] = A[M][K] @ Wt(tiled)^T + bias ----------------
// A row-major; Wt tiled [n/64][k/64][64][64]. 2-buffer, one __syncthreads per K-step.
// 4 waves; wave tile (BM/2)x(BN/2). XCD-chunked 1D grid swizzle.
// KSPLIT>1: grid = KSPLIT x base; split s handles K-range [s*K/KSPLIT, ...); MODE 1
// combines via fp32 atomicAdd (bias added by split 0 only).
template<int BM, int BN, int MODE, int KSPLIT>
__global__ __launch_bounds__(256) void kt_gemm(
    const u16* __restrict__ A, const u16* __restrict__ Wt, const float* __restrict__ bias,
    u16* __restrict__ outb, float* __restrict__ hres, u16* __restrict__ vT, int N, int K)
{
  constexpr int MF = BM / 32;
  constexpr int NF = BN / 32;
  constexpr int Mt = NTOK / BM;
  constexpr int Mx = Mt / 8;
  __shared__ __align__(16) u16 As[2][BM * 64];
  __shared__ __align__(16) u16 Bs[2][BN * 64];
  int tid = threadIdx.x, wave = tid >> 6, lane = tid & 63;

  int Nt = N / BN;
  int base = Mt * Nt;
  int bid = blockIdx.x;
  int split = (KSPLIT > 1) ? (bid / base) : 0;
  if (KSPLIT > 1) bid -= split * base;
  int Ks = K / KSPLIT;
  int kbase = split * Ks;

  int xcd = bid & 7, slot = bid >> 3;
  int miL = slot / Nt;
  int ni = slot - miL * Nt;
  int m0 = (xcd * Mx + miL) * BM, n0 = ni * BN;

  int wm = wave >> 1, wn = wave & 1;
  f32x4 acc[MF][NF];
  const f32x4 fzero = {0.f, 0.f, 0.f, 0.f};
  #pragma unroll
  for (int m = 0; m < MF; m++)
    #pragma unroll
    for (int n = 0; n < NF; n++) acc[m][n] = fzero;

  int srow = lane >> 3;
  int sblk = (lane & 7) ^ srow;
  const u16* gA = A + (size_t)(m0 + wave * 8 + srow) * K + kbase + sblk * 8;
  int K64 = K >> 6;
  int ktile0 = kbase >> 6;

  size_t btile[NF];
  int    bofs [NF];
  #pragma unroll
  for (int j = 0; j < NF; j++){
    int row = n0 + j * 32 + wave * 8 + srow;
    btile[j] = (size_t)(row >> 6) * K64;
    bofs[j]  = (row & 63) * 64 + sblk * 8;
  }

  auto stage = [&](int buf, int kt){
    #pragma unroll
    for (int j = 0; j < MF; j++)
      llds16(gA + (size_t)(j * 32) * K + kt, &As[buf][(j * 32 + wave * 8) * 64]);
    int ktile = ktile0 + (kt >> 6);
    #pragma unroll
    for (int j = 0; j < NF; j++)
      llds16(Wt + ((btile[j] + ktile) << 12) + bofs[j], &Bs[buf][(j * 32 + wave * 8) * 64]);
  };

  int nk = Ks >> 6;
  stage(0, 0);
  __syncthreads();
  int rl = lane & 15, hg = lane >> 4;
  for (int t = 0; t < nk; ++t){
    int cur = t & 1;
    if (t + 1 < nk) stage(cur ^ 1, (t + 1) << 6);
    #pragma unroll
    for (int kk = 0; kk < 2; kk++){
      bf16x8 af[MF], bfr[NF];
      int bl = (kk << 2) + hg;
      #pragma unroll
      for (int m = 0; m < MF; m++){
        int row = wm * (BM / 2) + m * 16 + rl;
        af[m] = *(const bf16x8*)&As[cur][row * 64 + ((bl ^ (row & 7)) << 3)];
      }
      #pragma unroll
      for (int n = 0; n < NF; n++){
        int row = wn * (BN / 2) + n * 16 + rl;
        bfr[n] = *(const bf16x8*)&Bs[cur][row * 64 + ((bl ^ (row & 7)) << 3)];
      }
      #pragma unroll
      for (int m = 0; m < MF; m++)
        #pragma unroll
        for (int n = 0; n < NF; n++)
          acc[m][n] = __builtin_amdgcn_mfma_f32_16x16x32_bf16(af[m], bfr[n], acc[m][n], 0, 0, 0);
    }
    __syncthreads();
  }

  int cl = lane & 15, rg = lane >> 4;
  #pragma unroll
  for (int m = 0; m < MF; m++){
    int row0 = m0 + wm * (BM / 2) + m * 16 + rg * 4;
    #pragma unroll
    for (int n = 0; n < NF; n++){
      int col = n0 + wn * (BN / 2) + n * 16 + cl;
      float bb = bias[col];
      if (MODE == 1){
        #pragma unroll
        for (int r = 0; r < 4; r++){
          size_t idx = (size_t)(row0 + r) * N + col;
          if (KSPLIT == 1){
            hres[idx] += acc[m][n][r] + bb;
          } else {
            float v = acc[m][n][r] + (split == 0 ? bb : 0.f);
            atomicAdd(&hres[idx], v);
          }
        }
      } else if (MODE == 2){
        #pragma unroll
        for (int r = 0; r < 4; r++){
          float x = acc[m][n][r] + bb;
          float t = 0.7978845608028654f * (x + 0.044715f * x * x * x);
          float sg = 1.0f / (1.0f + __expf(-2.0f * t));   // 0.5*(1+tanh(t)) == sigmoid(2t)
          outb[(size_t)(row0 + r) * N + col] = f2bf(x * sg);
        }
      } else {
        if (col < 1024){
          #pragma unroll
          for (int r = 0; r < 4; r++)
            outb[(size_t)(row0 + r) * N + col] = f2bf(acc[m][n][r] + bb);
        } else {
          int dh = col - 1024;
          int win = row0 >> 9, tin = row0 & 511;
          ushort4 p;
          p.x = f2bf(acc[m][n][0] + bb);
          p.y = f2bf(acc[m][n][1] + bb);
          p.z = f2bf(acc[m][n][2] + bb);
          p.w = f2bf(acc[m][n][3] + bb);
          *(ushort4*)&vT[(size_t)(win * 512 + dh) * 512 + tin] = p;
        }
      }
    }
  }
}

// ---------------- windowed flash attention: LDS-staged K/V (3-buf, counted vmcnt) -------
__global__ __launch_bounds__(256) void kt_attn(const u16* __restrict__ qkv,
                                               const u16* __restrict__ vT,
                                               u16* __restrict__ o){
  __shared__ __align__(16) u16 Ks[3][32 * 64];
  __shared__ __align__(16) u16 Vs[3][64 * 32];
  int tid = threadIdx.x, wave = tid >> 6, lane = tid & 63;
  int bx = blockIdx.x;
  int win = bx >> 6, head = (bx >> 3) & 7, q8 = bx & 7;
  int rl = lane & 15, hg = lane >> 4;
  int qbase = win * 512 + q8 * 64 + wave * 16;
  const u16* qptr  = qkv + (size_t)(qbase + rl) * QKVD + head * 64;
  const u16* kbase = qkv + (size_t)(win * 512) * QKVD + 512 + head * 64;
  const u16* vbase = vT + (size_t)(win * 512 + head * 64) * 512;

  int krow = tid >> 3;
  const u16* gK = kbase + (size_t)krow * QKVD + (((tid & 7) ^ (krow & 7)) << 3);
  int vrow = tid >> 2;
  const u16* gV = vbase + (size_t)vrow * 512 + (((tid & 3) ^ (vrow & 3)) << 3);

  auto stage = [&](int buf, int kt){
    llds16(gK + (size_t)kt * QKVD, &Ks[buf][tid * 8]);
    llds16(gV + kt, &Vs[buf][tid * 8]);
  };

  bf16x8 qf0 = *(const bf16x8*)(qptr + hg * 8);
  bf16x8 qf1 = *(const bf16x8*)(qptr + 32 + hg * 8);

  const f32x4 fzero = {0.f, 0.f, 0.f, 0.f};
  f32x4 Oa[4] = {fzero, fzero, fzero, fzero};
  float mrun = -1e30f, lrun = 0.f;

  stage(0, 0);
  stage(1, 32);
  for (int t = 0; t < 16; ++t){
    int cur = t % 3;
    if (t + 1 < 16) wait_vmcnt<2>(); else wait_vmcnt<0>();
    __builtin_amdgcn_s_barrier();
    asm volatile("" ::: "memory");
    if (t + 2 < 16) stage((t + 2) % 3, (t + 2) * 32);

    bf16x8 kf[2][2];
    #pragma unroll
    for (int c = 0; c < 2; c++)
      #pragma unroll
      for (int dk = 0; dk < 2; dk++){
        int row = c * 16 + rl;
        kf[c][dk] = *(const bf16x8*)&Ks[cur][row * 64 + ((((dk << 2) + hg) ^ (rl & 7)) << 3)];
      }
    bf16x8 vf[4];
    #pragma unroll
    for (int d = 0; d < 4; d++){
      int row = d * 16 + rl;
      vf[d] = *(const bf16x8*)&Vs[cur][row * 32 + ((hg ^ (rl & 3)) << 3)];
    }

    f32x4 s0 = fzero, s1 = fzero;
    s0 = __builtin_amdgcn_mfma_f32_16x16x32_bf16(kf[0][0], qf0, s0, 0, 0, 0);
    s0 = __builtin_amdgcn_mfma_f32_16x16x32_bf16(kf[0][1], qf1, s0, 0, 0, 0);
    s1 = __builtin_amdgcn_mfma_f32_16x16x32_bf16(kf[1][0], qf0, s1, 0, 0, 0);
    s1 = __builtin_amdgcn_mfma_f32_16x16x32_bf16(kf[1][1], qf1, s1, 0, 0, 0);
    float v[8];
    #pragma unroll
    for (int r = 0; r < 4; r++){ v[r] = s0[r] * 0.125f; v[4 + r] = s1[r] * 0.125f; }
    float tmax = v[0];
    #pragma unroll
    for (int i = 1; i < 8; i++) tmax = fmaxf(tmax, v[i]);
    tmax = fmaxf(tmax, __shfl_xor(tmax, 16));
    tmax = fmaxf(tmax, __shfl_xor(tmax, 32));
    float mnew = fmaxf(mrun, tmax);
    float corr = __expf(mrun - mnew);
    mrun = mnew;
    float p[8], ps = 0.f;
    #pragma unroll
    for (int i = 0; i < 8; i++){ p[i] = __expf(v[i] - mnew); ps += p[i]; }
    ps += __shfl_xor(ps, 16);
    ps += __shfl_xor(ps, 32);
    lrun = lrun * corr + ps;
    float c0 = __shfl(corr, (hg << 2) + 0);
    float c1 = __shfl(corr, (hg << 2) + 1);
    float c2 = __shfl(corr, (hg << 2) + 2);
    float c3 = __shfl(corr, (hg << 2) + 3);
    #pragma unroll
    for (int d = 0; d < 4; d++){
      Oa[d][0] *= c0; Oa[d][1] *= c1; Oa[d][2] *= c2; Oa[d][3] *= c3;
    }
    unsigned pk00 = pack2(p[0], p[1]);
    unsigned pk01 = pack2(p[2], p[3]);
    unsigned pk10 = pack2(p[4], p[5]);
    unsigned pk11 = pack2(p[6], p[7]);
    int idx0 = rl | ((( hg << 1)      & 3) << 4);
    int idx1 = rl | ((((hg << 1) + 1) & 3) << 4);
    bool hiC = hg >= 2;
    unsigned W0a = __shfl(pk00, idx0), W0b = __shfl(pk10, idx0);
    unsigned W1a = __shfl(pk01, idx0), W1b = __shfl(pk11, idx0);
    unsigned W2a = __shfl(pk00, idx1), W2b = __shfl(pk10, idx1);
    unsigned W3a = __shfl(pk01, idx1), W3b = __shfl(pk11, idx1);
    uint4 W;
    W.x = hiC ? W0b : W0a;
    W.y = hiC ? W1b : W1a;
    W.z = hiC ? W2b : W2a;
    W.w = hiC ? W3b : W3a;
    bf16x8 pf;
    __builtin_memcpy(&pf, &W, 16);
    #pragma unroll
    for (int d = 0; d < 4; d++)
      Oa[d] = __builtin_amdgcn_mfma_f32_16x16x32_bf16(pf, vf[d], Oa[d], 0, 0, 0);
  }

  float l0 = __shfl(lrun, (hg << 2) + 0);
  float l1 = __shfl(lrun, (hg << 2) + 1);
  float l2 = __shfl(lrun, (hg << 2) + 2);
  float l3 = __shfl(lrun, (hg << 2) + 3);
  float li[4] = {1.f / l0, 1.f / l1, 1.f / l2, 1.f / l3};
  #pragma unroll
  for (int d = 0; d < 4; d++)
    #pragma unroll
    for (int r = 0; r < 4; r++){
      int row = qbase + (hg << 2) + r;
      o[(size_t)row * CDIM + head * 64 + d * 16 + rl] = f2bf(Oa[d][r] * li[r]);
    }
}

// ------------- final: fused LN(eps 1e-5) + head GEMM (N=56 pad 64) + post-process -------
__global__ __launch_bounds__(256) void kt_final(const float* __restrict__ h,
                                                const u16* __restrict__ WoT,
                                                const float* __restrict__ b_out,
                                                const int* __restrict__ coords,
                                                const float* __restrict__ offp,
                                                float* __restrict__ out){
  __shared__ __align__(16) u16 As[2][64 * 64];
  __shared__ __align__(16) u16 Bs[2][64 * 64];
  __shared__ float Mu[64], Rs[64];
  int tid = threadIdx.x, wave = tid >> 6, lane = tid & 63;
  int m0 = blockIdx.x * 64;
  int wm = wave >> 1, wn = wave & 1;

  for (int rr = 0; rr < 16; ++rr){
    int rloc = wave * 16 + rr;
    const float* hp = h + (size_t)(m0 + rloc) * CDIM + lane * 8;
    float4 v0 = *(const float4*)hp, v1 = *(const float4*)(hp + 4);
    float x[8] = {v0.x, v0.y, v0.z, v0.w, v1.x, v1.y, v1.z, v1.w};
    float s = 0.f, q = 0.f;
    #pragma unroll
    for (int i = 0; i < 8; i++){ s += x[i]; q += x[i] * x[i]; }
    #pragma unroll
    for (int off = 32; off; off >>= 1){ s += __shfl_xor(s, off); q += __shfl_xor(q, off); }
    if (lane == 0){
      float mean = s * (1.0f / CDIM);
      float var  = q * (1.0f / CDIM) - mean * mean;
      Mu[rloc] = mean;
      Rs[rloc] = rsqrtf(var + 1e-5f);
    }
  }
  __syncthreads();

  int ar = tid >> 2, ac = tid & 3;
  float mu_ = Mu[ar], rs_ = Rs[ar];

  auto stageA = [&](int buf, int kt){
    const float* hp = h + (size_t)(m0 + ar) * CDIM + kt + ac * 16;
    float4 a0 = *(const float4*)hp, a1 = *(const float4*)(hp + 4);
    float4 a2 = *(const float4*)(hp + 8), a3 = *(const float4*)(hp + 12);
    float x[16] = {a0.x,a0.y,a0.z,a0.w, a1.x,a1.y,a1.z,a1.w,
                   a2.x,a2.y,a2.z,a2.w, a3.x,a3.y,a3.z,a3.w};
    u16 w[16];
    #pragma unroll
    for (int i = 0; i < 16; i++) w[i] = f2bf((x[i] - mu_) * rs_);
    uint4 p0, p1;
    p0.x = (unsigned)w[0] | ((unsigned)w[1] << 16);
    p0.y = (unsigned)w[2] | ((unsigned)w[3] << 16);
    p0.z = (unsigned)w[4] | ((unsigned)w[5] << 16);
    p0.w = (unsigned)w[6] | ((unsigned)w[7] << 16);
    p1.x = (unsigned)w[8] | ((unsigned)w[9] << 16);
    p1.y = (unsigned)w[10] | ((unsigned)w[11] << 16);
    p1.z = (unsigned)w[12] | ((unsigned)w[13] << 16);
    p1.w = (unsigned)w[14] | ((unsigned)w[15] << 16);
    int j0 = ac * 2, j1 = ac * 2 + 1;
    *(uint4*)&As[buf][ar * 64 + ((j0 ^ (ar & 7)) << 3)] = p0;
    *(uint4*)&As[buf][ar * 64 + ((j1 ^ (ar & 7)) << 3)] = p1;
  };

  int srow = lane >> 3;
  int sblk = (lane & 7) ^ srow;
  int bofs[2];
  #pragma unroll
  for (int j = 0; j < 2; j++)
    bofs[j] = (j * 32 + wave * 8 + srow) * 64 + sblk * 8;
  auto stageB = [&](int buf, int kt){
    int ktile = kt >> 6;
    #pragma unroll
    for (int j = 0; j < 2; j++)
      llds16(WoT + (ktile << 12) + bofs[j], &Bs[buf][(j * 32 + wave * 8) * 64]);
  };

  f32x4 acc[2][2];
  const f32x4 fzero = {0.f, 0.f, 0.f, 0.f};
  acc[0][0] = fzero; acc[0][1] = fzero; acc[1][0] = fzero; acc[1][1] = fzero;

  stageB(0, 0);
  stageA(0, 0);
  __syncthreads();
  int rl = lane & 15, hg = lane >> 4;
  for (int t = 0; t < 8; ++t){
    int cur = t & 1;
    if (t + 1 < 8){
      stageB(cur ^ 1, (t + 1) << 6);
      stageA(cur ^ 1, (t + 1) << 6);
    }
    #pragma unroll
    for (int kk = 0; kk < 2; kk++){
      bf16x8 af[2], bfr[2];
      int bl = (kk << 2) + hg;
      #pragma unroll
      for (int m = 0; m < 2; m++){
        int row = wm * 32 + m * 16 + rl;
        af[m] = *(const bf16x8*)&As[cur][row * 64 + ((bl ^ (row & 7)) << 3)];
      }
      #pragma unroll
      for (int n = 0; n < 2; n++){
        int row = wn * 32 + n * 16 + rl;
        bfr[n] = *(const bf16x8*)&Bs[cur][row * 64 + ((bl ^ (row & 7)) << 3)];
      }
      #pragma unroll
      for (int m = 0; m < 2; m++)
        #pragma unroll
        for (int n = 0; n < 2; n++)
          acc[m][n] = __builtin_amdgcn_mfma_f32_16x16x32_bf16(af[m], bfr[n], acc[m][n], 0, 0, 0);
    }
    __syncthreads();
  }

  int cl = lane & 15, rg = lane >> 4;
  #pragma unroll
  for (int m = 0; m < 2; m++){
    int row0 = m0 + wm * 32 + m * 16 + rg * 4;
    #pragma unroll
    for (int n = 0; n < 2; n++){
      int col = wn * 32 + n * 16 + cl;
      if (col < 56){
        float bb = b_out[col];
        #pragma unroll
        for (int r = 0; r < 4; r++){
          int row = row0 + r;
          float v = acc[m][n][r] + bb;
          if (col < 12){
            int d = col - (col / 3) * 3;
            float base = ((float)coords[row * 4 + 1 + d] + 0.5f) * (1.0f / 16.0f);
            float tt = tanhf(v + offp[col]);
            out[(size_t)row * 12 + col] = base + tt * 4.8828125e-4f;
          } else if (col < 24){
            out[49152 + (size_t)row * 12 + (col - 12)] = v;
          } else if (col < 36){
            out[98304 + (size_t)row * 12 + (col - 24)] = v;
          } else if (col < 52){
            out[147456 + (size_t)row * 16 + (col - 36)] = v;
          } else {
            out[212992 + (size_t)row * 4 + (col - 52)] = v;
          }
        }
      }
    }
  }
}

extern "C" void kernel_launch(void* const* d_in, const int* in_sizes, int n_in,
                              void* d_out, int out_size, void* d_ws, size_t ws_size,
                              hipStream_t stream) {
  const float* feats = (const float*)d_in[0];
  const int*   coords = (const int*)d_in[1];
  const float* emb_x = (const float*)d_in[2];
  const float* emb_y = (const float*)d_in[3];
  const float* emb_z = (const float*)d_in[4];
  const float* w_in  = (const float*)d_in[5];
  const float* b_in  = (const float*)d_in[6];
  const float* ln1_g = (const float*)d_in[7];
  const float* ln1_b = (const float*)d_in[8];
  const float* w_qkv = (const float*)d_in[9];
  const float* b_qkv = (const float*)d_in[10];
  const float* w_o   = (const float*)d_in[11];
  const float* b_o   = (const float*)d_in[12];
  const float* ln2_g = (const float*)d_in[13];
  const float* ln2_b = (const float*)d_in[14];
  const float* w_m1  = (const float*)d_in[15];
  const float* b_m1  = (const float*)d_in[16];
  const float* w_m2  = (const float*)d_in[17];
  const float* b_m2  = (const float*)d_in[18];
  const float* w_out = (const float*)d_in[19];
  const float* b_out = (const float*)d_in[20];
  const float* offp  = (const float*)d_in[21];

  char* ws = (char*)d_ws;
  auto carve = [&](size_t bytes){ char* p = ws; ws += (bytes + 255) & ~(size_t)255; return p; };
  float* h   = (float*)carve((size_t)NTOK * CDIM * 4);
  u16* a     = (u16*)carve((size_t)NTOK * CDIM * 2);
  u16* qkvb  = (u16*)carve((size_t)NTOK * QKVD * 2);
  u16* vT    = (u16*)carve((size_t)NTOK * CDIM * 2);
  u16* ob    = (u16*)carve((size_t)NTOK * CDIM * 2);
  u16* ub    = (u16*)carve((size_t)NTOK * MLPD * 2);
  u16* wqkvT = (u16*)carve((size_t)LAYERS * QKVD * CDIM * 2);
  u16* woT   = (u16*)carve((size_t)LAYERS * CDIM * CDIM * 2);
  u16* wm1T  = (u16*)carve((size_t)LAYERS * MLPD * CDIM * 2);
  u16* wm2T  = (u16*)carve((size_t)LAYERS * CDIM * MLPD * 2);
  u16* woutT = (u16*)carve((size_t)64 * CDIM * 2);

  kt_prologue<<<10248, 256, 0, stream>>>(w_qkv, w_o, w_m1, w_m2, w_out,
                                         wqkvT, woT, wm1T, wm2T, woutT,
                                         feats, coords, emb_x, emb_y, emb_z, w_in, b_in, h);

  for (int l = 0; l < LAYERS; ++l){
    kt_ln<<<NTOK/4, 256, 0, stream>>>(h, ln1_g + l*CDIM, ln1_b + l*CDIM, a, 1e-6f);
    kt_gemm<64,64,0,1><<<(NTOK/64)*(QKVD/64), 256, 0, stream>>>(
        a, wqkvT + (size_t)l*QKVD*CDIM, b_qkv + l*QKVD, qkvb, nullptr, vT, QKVD, CDIM);
    kt_attn<<<512, 256, 0, stream>>>(qkvb, vT, ob);
    kt_gemm<64,64,1,1><<<(NTOK/64)*(CDIM/64), 256, 0, stream>>>(
        ob, woT + (size_t)l*CDIM*CDIM, b_o + l*CDIM, nullptr, h, nullptr, CDIM, CDIM);
    kt_ln<<<NTOK/4, 256, 0, stream>>>(h, ln2_g + l*CDIM, ln2_b + l*CDIM, a, 1e-6f);
    kt_gemm<64,64,2,1><<<(NTOK/64)*(MLPD/64), 256, 0, stream>>>(
        a, wm1T + (size_t)l*MLPD*CDIM, b_m1 + l*MLPD, ub, nullptr, nullptr, MLPD, CDIM);
    kt_gemm<64,64,1,2><<<2*(NTOK/64)*(CDIM/64), 256, 0, stream>>>(
        ub, wm2T + (size_t)l*CDIM*MLPD, b_m2 + l*CDIM, nullptr, h, nullptr, CDIM, MLPD);
  }
  kt_final<<<64, 256, 0, stream>>>(h, woutT, b_out, coords, offp, (float*)d_out);
}

// Round 16
// 841.035 us; speedup vs baseline: 1.0070x; 1.0070x over previous
//
#include <hip/hip_runtime.h>
#include <stdint.h>

typedef unsigned short u16;
typedef short bf16x8 __attribute__((ext_vector_type(8)));
typedef float f32x4 __attribute__((ext_vector_type(4)));

#define NTOK 4096
#define CDIM 512
#define NHEAD 8
#define LAYERS 8
#define MLPD 2048
#define QKVD 1536

__device__ __forceinline__ u16 f2bf(float f){
  union { float f; unsigned u; } c; c.f = f;
  return (u16)((c.u + 0x7FFFu + ((c.u >> 16) & 1u)) >> 16);
}

__device__ __forceinline__ void llds16(const void* g, void* l){
  __builtin_amdgcn_global_load_lds((const __attribute__((address_space(1))) void*)g,
                                   (__attribute__((address_space(3))) void*)l, 16, 0, 0);
}

template<int N> __device__ __forceinline__ void wait_vmcnt(){
  if constexpr (N == 0) asm volatile("s_waitcnt vmcnt(0)" ::: "memory");
  else if constexpr (N == 2) asm volatile("s_waitcnt vmcnt(2)" ::: "memory");
  else if constexpr (N == 4) asm volatile("s_waitcnt vmcnt(4)" ::: "memory");
  else static_assert(N == 0 || N == 2 || N == 4, "unsupported vmcnt");
}

// ------- merged prologue: weight transpose+convert (tiled bf16) + token embed ----------
// Wt layout: [n/64][k/64][64][64]. blocks 0..6143 transpose, 6144..6151 w_out (guarded),
// 6152..10247 embed (one token each). 10248 blocks.
__global__ void kt_prologue(const float* __restrict__ wqkv, const float* __restrict__ wo,
                            const float* __restrict__ wm1, const float* __restrict__ wm2,
                            const float* __restrict__ wout,
                            u16* __restrict__ qkvT, u16* __restrict__ oT,
                            u16* __restrict__ m1T, u16* __restrict__ m2T,
                            u16* __restrict__ outT,
                            const float* __restrict__ feats, const int* __restrict__ coords,
                            const float* __restrict__ ex, const float* __restrict__ ey,
                            const float* __restrict__ ez, const float* __restrict__ w_in,
                            const float* __restrict__ b_in, float* __restrict__ h){
  __shared__ float tile[64][65];
  __shared__ float fs[8];
  __shared__ int ccx[3];
  int bid = blockIdx.x;
  int t = threadIdx.x;

  if (bid >= 6152){           // ---- embed segment ----
    int n = bid - 6152;
    if (t < 8) fs[t] = feats[n * 8 + t];
    if (t == 8) { ccx[0] = coords[n*4+1]; ccx[1] = coords[n*4+2]; ccx[2] = coords[n*4+3]; }
    __syncthreads();
    for (int c = t; c < CDIM; c += 256){
      float acc = b_in[c];
      #pragma unroll
      for (int i = 0; i < 8; i++) acc += fs[i] * w_in[i * CDIM + c];
      float pe;
      if (c < 170)      pe = ex[ccx[0] * 170 + c];
      else if (c < 340) pe = ey[ccx[1] * 170 + (c - 170)];
      else              pe = ez[ccx[2] * 172 + (c - 340)];
      h[(size_t)n * CDIM + c] = acc + pe;
    }
    return;
  }

  const float* W; u16* Wt; int K, N, k0, n0; bool guard = false;
  if (bid < 1536){            // qkv: 24 n-tiles x 8 k-tiles per layer
    int l = bid / 192, r = bid % 192;
    W = wqkv + (size_t)l * 512 * 1536; Wt = qkvT + (size_t)l * 512 * 1536;
    K = 512; N = 1536; n0 = (r % 24) * 64; k0 = (r / 24) * 64;
  } else if (bid < 2048){     // o: 8 x 8
    int b = bid - 1536; int l = b / 64, r = b % 64;
    W = wo + (size_t)l * 512 * 512; Wt = oT + (size_t)l * 512 * 512;
    K = 512; N = 512; n0 = (r % 8) * 64; k0 = (r / 8) * 64;
  } else if (bid < 4096){     // m1: 32 x 8
    int b = bid - 2048; int l = b / 256, r = b % 256;
    W = wm1 + (size_t)l * 512 * 2048; Wt = m1T + (size_t)l * 512 * 2048;
    K = 512; N = 2048; n0 = (r % 32) * 64; k0 = (r / 32) * 64;
  } else if (bid < 6144){     // m2: 8 x 32
    int b = bid - 4096; int l = b / 256, r = b % 256;
    W = wm2 + (size_t)l * 2048 * 512; Wt = m2T + (size_t)l * 2048 * 512;
    K = 2048; N = 512; n0 = (r % 8) * 64; k0 = (r / 8) * 64;
  } else {                    // w_out: 1 n-tile (56 guarded, pad 64) x 8 k-tiles
    int r = bid - 6144;
    W = wout; Wt = outT;
    K = 512; N = 56; n0 = 0; k0 = r * 64;
    guard = true;
  }
  int kr = t >> 4, cc = (t & 15) << 2;
  if (guard){
    #pragma unroll
    for (int j = 0; j < 4; j++)
      #pragma unroll
      for (int i = 0; i < 4; i++){
        int col = n0 + cc + i;
        tile[kr + j * 16][cc + i] = (col < N) ? W[(size_t)(k0 + kr + j * 16) * N + col] : 0.f;
      }
  } else {
    #pragma unroll
    for (int j = 0; j < 4; j++){
      float4 v = *(const float4*)&W[(size_t)(k0 + kr + j * 16) * N + n0 + cc];
      tile[kr + j * 16][cc + 0] = v.x;
      tile[kr + j * 16][cc + 1] = v.y;
      tile[kr + j * 16][cc + 2] = v.z;
      tile[kr + j * 16][cc + 3] = v.w;
    }
  }
  __syncthreads();
  size_t tbase = ((size_t)(n0 >> 6) * (K >> 6) + (k0 >> 6)) << 12;
  int nr = t >> 3, kc = (t & 7) << 3;
  #pragma unroll
  for (int s = 0; s < 2; s++){
    int n = nr + s * 32;
    uint4 p;
    p.x = (unsigned)f2bf(tile[kc + 0][n]) | ((unsigned)f2bf(tile[kc + 1][n]) << 16);
    p.y = (unsigned)f2bf(tile[kc + 2][n]) | ((unsigned)f2bf(tile[kc + 3][n]) << 16);
    p.z = (unsigned)f2bf(tile[kc + 4][n]) | ((unsigned)f2bf(tile[kc + 5][n]) << 16);
    p.w = (unsigned)f2bf(tile[kc + 6][n]) | ((unsigned)f2bf(tile[kc + 7][n]) << 16);
    *(uint4*)&Wt[tbase + (size_t)n * 64 + kc] = p;
  }
}

// ---------------- LayerNorm: fp32 h -> bf16 out ----------------
__global__ void kt_ln(const float* __restrict__ h, const float* __restrict__ g,
                      const float* __restrict__ b, u16* __restrict__ out, float eps){
  int wave = threadIdx.x >> 6, lane = threadIdx.x & 63;
  int row = blockIdx.x * 4 + wave;
  const float* hr = h + (size_t)row * CDIM + lane * 8;
  float4 v0 = *(const float4*)hr, v1 = *(const float4*)(hr + 4);
  float x[8] = {v0.x, v0.y, v0.z, v0.w, v1.x, v1.y, v1.z, v1.w};
  float s = 0.f, q = 0.f;
  #pragma unroll
  for (int i = 0; i < 8; i++){ s += x[i]; q += x[i] * x[i]; }
  #pragma unroll
  for (int off = 32; off; off >>= 1){ s += __shfl_xor(s, off); q += __shfl_xor(q, off); }
  float mean = s * (1.0f / CDIM);
  float var  = q * (1.0f / CDIM) - mean * mean;
  float rr = rsqrtf(var + eps);
  int cb = lane * 8;
  u16 u[8];
  #pragma unroll
  for (int i = 0; i < 8; i++)
    u[i] = f2bf((x[i] - mean) * rr * g[cb + i] + b[cb + i]);
  uint4 pk;
  pk.x = (unsigned)u[0] | ((unsigned)u[1] << 16);
  pk.y = (unsigned)u[2] | ((unsigned)u[3] << 16);
  pk.z = (unsigned)u[4] | ((unsigned)u[5] << 16);
  pk.w = (unsigned)u[6] | ((unsigned)u[7] << 16);
  *(uint4*)&out[(size_t)row * CDIM + cb] = pk;
}

// ---------------- bf16 GEMM: C[M=4096][N] = A[M][K] @ Wt(tiled)^T + bias ----------------
// A row-major; Wt tiled [n/64][k/64][64][64]. 2-buffer, one __syncthreads per K-step.
// 4 waves; wave tile (BM/2)x(BN/2). XCD-chunked 1D grid swizzle.
template<int BM, int BN, int MODE>
__global__ __launch_bounds__(256) void kt_gemm(
    const u16* __restrict__ A, const u16* __restrict__ Wt, const float* __restrict__ bias,
    u16* __restrict__ outb, float* __restrict__ hres, u16* __restrict__ vT, int N, int K)
{
  constexpr int MF = BM / 32;
  constexpr int NF = BN / 32;
  constexpr int Mt = NTOK / BM;
  constexpr int Mx = Mt / 8;
  __shared__ __align__(16) u16 As[2][BM * 64];
  __shared__ __align__(16) u16 Bs[2][BN * 64];
  int tid = threadIdx.x, wave = tid >> 6, lane = tid & 63;

  int Nt = N / BN;
  int bid = blockIdx.x;
  int xcd = bid & 7, slot = bid >> 3;
  int miL = slot / Nt;
  int ni = slot - miL * Nt;
  int m0 = (xcd * Mx + miL) * BM, n0 = ni * BN;

  int wm = wave >> 1, wn = wave & 1;
  f32x4 acc[MF][NF];
  const f32x4 fzero = {0.f, 0.f, 0.f, 0.f};
  #pragma unroll
  for (int m = 0; m < MF; m++)
    #pragma unroll
    for (int n = 0; n < NF; n++) acc[m][n] = fzero;

  int srow = lane >> 3;
  int sblk = (lane & 7) ^ srow;
  const u16* gA = A + (size_t)(m0 + wave * 8 + srow) * K + sblk * 8;
  int K64 = K >> 6;

  size_t btile[NF];
  int    bofs [NF];
  #pragma unroll
  for (int j = 0; j < NF; j++){
    int row = n0 + j * 32 + wave * 8 + srow;
    btile[j] = (size_t)(row >> 6) * K64;
    bofs[j]  = (row & 63) * 64 + sblk * 8;
  }

  auto stage = [&](int buf, int kt){
    #pragma unroll
    for (int j = 0; j < MF; j++)
      llds16(gA + (size_t)(j * 32) * K + kt, &As[buf][(j * 32 + wave * 8) * 64]);
    int ktile = kt >> 6;
    #pragma unroll
    for (int j = 0; j < NF; j++)
      llds16(Wt + ((btile[j] + ktile) << 12) + bofs[j], &Bs[buf][(j * 32 + wave * 8) * 64]);
  };

  int nk = K >> 6;
  stage(0, 0);
  __syncthreads();
  int rl = lane & 15, hg = lane >> 4;
  for (int t = 0; t < nk; ++t){
    int cur = t & 1;
    if (t + 1 < nk) stage(cur ^ 1, (t + 1) << 6);
    #pragma unroll
    for (int kk = 0; kk < 2; kk++){
      bf16x8 af[MF], bfr[NF];
      int bl = (kk << 2) + hg;
      #pragma unroll
      for (int m = 0; m < MF; m++){
        int row = wm * (BM / 2) + m * 16 + rl;
        af[m] = *(const bf16x8*)&As[cur][row * 64 + ((bl ^ (row & 7)) << 3)];
      }
      #pragma unroll
      for (int n = 0; n < NF; n++){
        int row = wn * (BN / 2) + n * 16 + rl;
        bfr[n] = *(const bf16x8*)&Bs[cur][row * 64 + ((bl ^ (row & 7)) << 3)];
      }
      #pragma unroll
      for (int m = 0; m < MF; m++)
        #pragma unroll
        for (int n = 0; n < NF; n++)
          acc[m][n] = __builtin_amdgcn_mfma_f32_16x16x32_bf16(af[m], bfr[n], acc[m][n], 0, 0, 0);
    }
    __syncthreads();
  }

  int cl = lane & 15, rg = lane >> 4;
  #pragma unroll
  for (int m = 0; m < MF; m++){
    int row0 = m0 + wm * (BM / 2) + m * 16 + rg * 4;
    #pragma unroll
    for (int n = 0; n < NF; n++){
      int col = n0 + wn * (BN / 2) + n * 16 + cl;
      float bb = bias[col];
      if (MODE == 1){
        #pragma unroll
        for (int r = 0; r < 4; r++){
          size_t idx = (size_t)(row0 + r) * N + col;
          hres[idx] += acc[m][n][r] + bb;
        }
      } else if (MODE == 2){
        #pragma unroll
        for (int r = 0; r < 4; r++){
          float x = acc[m][n][r] + bb;
          float t = 0.7978845608028654f * (x + 0.044715f * x * x * x);
          float sg = 1.0f / (1.0f + __expf(-2.0f * t));   // 0.5*(1+tanh(t)) == sigmoid(2t)
          outb[(size_t)(row0 + r) * N + col] = f2bf(x * sg);
        }
      } else {
        if (col < 1024){
          #pragma unroll
          for (int r = 0; r < 4; r++)
            outb[(size_t)(row0 + r) * N + col] = f2bf(acc[m][n][r] + bb);
        } else {
          int dh = col - 1024;
          int win = row0 >> 9, tin = row0 & 511;
          ushort4 p;
          p.x = f2bf(acc[m][n][0] + bb);
          p.y = f2bf(acc[m][n][1] + bb);
          p.z = f2bf(acc[m][n][2] + bb);
          p.w = f2bf(acc[m][n][3] + bb);
          *(ushort4*)&vT[(size_t)(win * 512 + dh) * 512 + tin] = p;
        }
      }
    }
  }
}

// ---------------- windowed flash attention: LDS-staged K/V (3-buf, counted vmcnt) -------
__global__ __launch_bounds__(256) void kt_attn(const u16* __restrict__ qkv,
                                               const u16* __restrict__ vT,
                                               u16* __restrict__ o){
  __shared__ __align__(16) u16 Ks[3][32 * 64];
  __shared__ __align__(16) u16 Vs[3][64 * 32];
  int tid = threadIdx.x, wave = tid >> 6, lane = tid & 63;
  int bx = blockIdx.x;
  int win = bx >> 6, head = (bx >> 3) & 7, q8 = bx & 7;
  int rl = lane & 15, hg = lane >> 4;
  int qbase = win * 512 + q8 * 64 + wave * 16;
  const u16* qptr  = qkv + (size_t)(qbase + rl) * QKVD + head * 64;
  const u16* kbase = qkv + (size_t)(win * 512) * QKVD + 512 + head * 64;
  const u16* vbase = vT + (size_t)(win * 512 + head * 64) * 512;

  int krow = tid >> 3;
  const u16* gK = kbase + (size_t)krow * QKVD + (((tid & 7) ^ (krow & 7)) << 3);
  int vrow = tid >> 2;
  const u16* gV = vbase + (size_t)vrow * 512 + (((tid & 3) ^ (vrow & 3)) << 3);

  auto stage = [&](int buf, int kt){
    llds16(gK + (size_t)kt * QKVD, &Ks[buf][tid * 8]);
    llds16(gV + kt, &Vs[buf][tid * 8]);
  };

  bf16x8 qf0 = *(const bf16x8*)(qptr + hg * 8);
  bf16x8 qf1 = *(const bf16x8*)(qptr + 32 + hg * 8);

  const f32x4 fzero = {0.f, 0.f, 0.f, 0.f};
  f32x4 Oa[4] = {fzero, fzero, fzero, fzero};
  float mrun = -1e30f, lrun = 0.f;

  stage(0, 0);
  stage(1, 32);
  for (int t = 0; t < 16; ++t){
    int cur = t % 3;
    if (t + 1 < 16) wait_vmcnt<2>(); else wait_vmcnt<0>();
    __builtin_amdgcn_s_barrier();
    asm volatile("" ::: "memory");
    if (t + 2 < 16) stage((t + 2) % 3, (t + 2) * 32);

    bf16x8 kf[2][2];
    #pragma unroll
    for (int c = 0; c < 2; c++)
      #pragma unroll
      for (int dk = 0; dk < 2; dk++){
        int row = c * 16 + rl;
        kf[c][dk] = *(const bf16x8*)&Ks[cur][row * 64 + ((((dk << 2) + hg) ^ (rl & 7)) << 3)];
      }
    bf16x8 vf[4];
    #pragma unroll
    for (int d = 0; d < 4; d++){
      int row = d * 16 + rl;
      vf[d] = *(const bf16x8*)&Vs[cur][row * 32 + ((hg ^ (rl & 3)) << 3)];
    }

    f32x4 s0 = fzero, s1 = fzero;
    s0 = __builtin_amdgcn_mfma_f32_16x16x32_bf16(kf[0][0], qf0, s0, 0, 0, 0);
    s0 = __builtin_amdgcn_mfma_f32_16x16x32_bf16(kf[0][1], qf1, s0, 0, 0, 0);
    s1 = __builtin_amdgcn_mfma_f32_16x16x32_bf16(kf[1][0], qf0, s1, 0, 0, 0);
    s1 = __builtin_amdgcn_mfma_f32_16x16x32_bf16(kf[1][1], qf1, s1, 0, 0, 0);
    float v[8];
    #pragma unroll
    for (int r = 0; r < 4; r++){ v[r] = s0[r] * 0.125f; v[4 + r] = s1[r] * 0.125f; }
    float tmax = v[0];
    #pragma unroll
    for (int i = 1; i < 8; i++) tmax = fmaxf(tmax, v[i]);
    tmax = fmaxf(tmax, __shfl_xor(tmax, 16));
    tmax = fmaxf(tmax, __shfl_xor(tmax, 32));
    float mnew = fmaxf(mrun, tmax);
    float corr = __expf(mrun - mnew);
    mrun = mnew;
    float p[8], ps = 0.f;
    #pragma unroll
    for (int i = 0; i < 8; i++){ p[i] = __expf(v[i] - mnew); ps += p[i]; }
    ps += __shfl_xor(ps, 16);
    ps += __shfl_xor(ps, 32);
    lrun = lrun * corr + ps;
    float c0 = __shfl(corr, (hg << 2) + 0);
    float c1 = __shfl(corr, (hg << 2) + 1);
    float c2 = __shfl(corr, (hg << 2) + 2);
    float c3 = __shfl(corr, (hg << 2) + 3);
    #pragma unroll
    for (int d = 0; d < 4; d++){
      Oa[d][0] *= c0; Oa[d][1] *= c1; Oa[d][2] *= c2; Oa[d][3] *= c3;
    }
    unsigned pk00 = (unsigned)f2bf(p[0]) | ((unsigned)f2bf(p[1]) << 16);
    unsigned pk01 = (unsigned)f2bf(p[2]) | ((unsigned)f2bf(p[3]) << 16);
    unsigned pk10 = (unsigned)f2bf(p[4]) | ((unsigned)f2bf(p[5]) << 16);
    unsigned pk11 = (unsigned)f2bf(p[6]) | ((unsigned)f2bf(p[7]) << 16);
    int idx0 = rl | ((( hg << 1)      & 3) << 4);
    int idx1 = rl | ((((hg << 1) + 1) & 3) << 4);
    bool hiC = hg >= 2;
    unsigned W0a = __shfl(pk00, idx0), W0b = __shfl(pk10, idx0);
    unsigned W1a = __shfl(pk01, idx0), W1b = __shfl(pk11, idx0);
    unsigned W2a = __shfl(pk00, idx1), W2b = __shfl(pk10, idx1);
    unsigned W3a = __shfl(pk01, idx1), W3b = __shfl(pk11, idx1);
    uint4 W;
    W.x = hiC ? W0b : W0a;
    W.y = hiC ? W1b : W1a;
    W.z = hiC ? W2b : W2a;
    W.w = hiC ? W3b : W3a;
    bf16x8 pf;
    __builtin_memcpy(&pf, &W, 16);
    #pragma unroll
    for (int d = 0; d < 4; d++)
      Oa[d] = __builtin_amdgcn_mfma_f32_16x16x32_bf16(pf, vf[d], Oa[d], 0, 0, 0);
  }

  float l0 = __shfl(lrun, (hg << 2) + 0);
  float l1 = __shfl(lrun, (hg << 2) + 1);
  float l2 = __shfl(lrun, (hg << 2) + 2);
  float l3 = __shfl(lrun, (hg << 2) + 3);
  float li[4] = {1.f / l0, 1.f / l1, 1.f / l2, 1.f / l3};
  #pragma unroll
  for (int d = 0; d < 4; d++)
    #pragma unroll
    for (int r = 0; r < 4; r++){
      int row = qbase + (hg << 2) + r;
      o[(size_t)row * CDIM + head * 64 + d * 16 + rl] = f2bf(Oa[d][r] * li[r]);
    }
}

// ------------- final: fused LN(eps 1e-5) + head GEMM (N=56 pad 64) + post-process -------
__global__ __launch_bounds__(256) void kt_final(const float* __restrict__ h,
                                                const u16* __restrict__ WoT,
                                                const float* __restrict__ b_out,
                                                const int* __restrict__ coords,
                                                const float* __restrict__ offp,
                                                float* __restrict__ out){
  __shared__ __align__(16) u16 As[2][64 * 64];
  __shared__ __align__(16) u16 Bs[2][64 * 64];
  __shared__ float Mu[64], Rs[64];
  int tid = threadIdx.x, wave = tid >> 6, lane = tid & 63;
  int m0 = blockIdx.x * 64;
  int wm = wave >> 1, wn = wave & 1;

  for (int rr = 0; rr < 16; ++rr){
    int rloc = wave * 16 + rr;
    const float* hp = h + (size_t)(m0 + rloc) * CDIM + lane * 8;
    float4 v0 = *(const float4*)hp, v1 = *(const float4*)(hp + 4);
    float x[8] = {v0.x, v0.y, v0.z, v0.w, v1.x, v1.y, v1.z, v1.w};
    float s = 0.f, q = 0.f;
    #pragma unroll
    for (int i = 0; i < 8; i++){ s += x[i]; q += x[i] * x[i]; }
    #pragma unroll
    for (int off = 32; off; off >>= 1){ s += __shfl_xor(s, off); q += __shfl_xor(q, off); }
    if (lane == 0){
      float mean = s * (1.0f / CDIM);
      float var  = q * (1.0f / CDIM) - mean * mean;
      Mu[rloc] = mean;
      Rs[rloc] = rsqrtf(var + 1e-5f);
    }
  }
  __syncthreads();

  int ar = tid >> 2, ac = tid & 3;
  float mu_ = Mu[ar], rs_ = Rs[ar];

  auto stageA = [&](int buf, int kt){
    const float* hp = h + (size_t)(m0 + ar) * CDIM + kt + ac * 16;
    float4 a0 = *(const float4*)hp, a1 = *(const float4*)(hp + 4);
    float4 a2 = *(const float4*)(hp + 8), a3 = *(const float4*)(hp + 12);
    float x[16] = {a0.x,a0.y,a0.z,a0.w, a1.x,a1.y,a1.z,a1.w,
                   a2.x,a2.y,a2.z,a2.w, a3.x,a3.y,a3.z,a3.w};
    u16 w[16];
    #pragma unroll
    for (int i = 0; i < 16; i++) w[i] = f2bf((x[i] - mu_) * rs_);
    uint4 p0, p1;
    p0.x = (unsigned)w[0] | ((unsigned)w[1] << 16);
    p0.y = (unsigned)w[2] | ((unsigned)w[3] << 16);
    p0.z = (unsigned)w[4] | ((unsigned)w[5] << 16);
    p0.w = (unsigned)w[6] | ((unsigned)w[7] << 16);
    p1.x = (unsigned)w[8] | ((unsigned)w[9] << 16);
    p1.y = (unsigned)w[10] | ((unsigned)w[11] << 16);
    p1.z = (unsigned)w[12] | ((unsigned)w[13] << 16);
    p1.w = (unsigned)w[14] | ((unsigned)w[15] << 16);
    int j0 = ac * 2, j1 = ac * 2 + 1;
    *(uint4*)&As[buf][ar * 64 + ((j0 ^ (ar & 7)) << 3)] = p0;
    *(uint4*)&As[buf][ar * 64 + ((j1 ^ (ar & 7)) << 3)] = p1;
  };

  int srow = lane >> 3;
  int sblk = (lane & 7) ^ srow;
  int bofs[2];
  #pragma unroll
  for (int j = 0; j < 2; j++)
    bofs[j] = (j * 32 + wave * 8 + srow) * 64 + sblk * 8;
  auto stageB = [&](int buf, int kt){
    int ktile = kt >> 6;
    #pragma unroll
    for (int j = 0; j < 2; j++)
      llds16(WoT + (ktile << 12) + bofs[j], &Bs[buf][(j * 32 + wave * 8) * 64]);
  };

  f32x4 acc[2][2];
  const f32x4 fzero = {0.f, 0.f, 0.f, 0.f};
  acc[0][0] = fzero; acc[0][1] = fzero; acc[1][0] = fzero; acc[1][1] = fzero;

  stageB(0, 0);
  stageA(0, 0);
  __syncthreads();
  int rl = lane & 15, hg = lane >> 4;
  for (int t = 0; t < 8; ++t){
    int cur = t & 1;
    if (t + 1 < 8){
      stageB(cur ^ 1, (t + 1) << 6);
      stageA(cur ^ 1, (t + 1) << 6);
    }
    #pragma unroll
    for (int kk = 0; kk < 2; kk++){
      bf16x8 af[2], bfr[2];
      int bl = (kk << 2) + hg;
      #pragma unroll
      for (int m = 0; m < 2; m++){
        int row = wm * 32 + m * 16 + rl;
        af[m] = *(const bf16x8*)&As[cur][row * 64 + ((bl ^ (row & 7)) << 3)];
      }
      #pragma unroll
      for (int n = 0; n < 2; n++){
        int row = wn * 32 + n * 16 + rl;
        bfr[n] = *(const bf16x8*)&Bs[cur][row * 64 + ((bl ^ (row & 7)) << 3)];
      }
      #pragma unroll
      for (int m = 0; m < 2; m++)
        #pragma unroll
        for (int n = 0; n < 2; n++)
          acc[m][n] = __builtin_amdgcn_mfma_f32_16x16x32_bf16(af[m], bfr[n], acc[m][n], 0, 0, 0);
    }
    __syncthreads();
  }

  int cl = lane & 15, rg = lane >> 4;
  #pragma unroll
  for (int m = 0; m < 2; m++){
    int row0 = m0 + wm * 32 + m * 16 + rg * 4;
    #pragma unroll
    for (int n = 0; n < 2; n++){
      int col = wn * 32 + n * 16 + cl;
      if (col < 56){
        float bb = b_out[col];
        #pragma unroll
        for (int r = 0; r < 4; r++){
          int row = row0 + r;
          float v = acc[m][n][r] + bb;
          if (col < 12){
            int d = col - (col / 3) * 3;
            float base = ((float)coords[row * 4 + 1 + d] + 0.5f) * (1.0f / 16.0f);
            float tt = tanhf(v + offp[col]);
            out[(size_t)row * 12 + col] = base + tt * 4.8828125e-4f;
          } else if (col < 24){
            out[49152 + (size_t)row * 12 + (col - 12)] = v;
          } else if (col < 36){
            out[98304 + (size_t)row * 12 + (col - 24)] = v;
          } else if (col < 52){
            out[147456 + (size_t)row * 16 + (col - 36)] = v;
          } else {
            out[212992 + (size_t)row * 4 + (col - 52)] = v;
          }
        }
      }
    }
  }
}

extern "C" void kernel_launch(void* const* d_in, const int* in_sizes, int n_in,
                              void* d_out, int out_size, void* d_ws, size_t ws_size,
                              hipStream_t stream) {
  const float* feats = (const float*)d_in[0];
  const int*   coords = (const int*)d_in[1];
  const float* emb_x = (const float*)d_in[2];
  const float* emb_y = (const float*)d_in[3];
  const float* emb_z = (const float*)d_in[4];
  const float* w_in  = (const float*)d_in[5];
  const float* b_in  = (const float*)d_in[6];
  const float* ln1_g = (const float*)d_in[7];
  const float* ln1_b = (const float*)d_in[8];
  const float* w_qkv = (const float*)d_in[9];
  const float* b_qkv = (const float*)d_in[10];
  const float* w_o   = (const float*)d_in[11];
  const float* b_o   = (const float*)d_in[12];
  const float* ln2_g = (const float*)d_in[13];
  const float* ln2_b = (const float*)d_in[14];
  const float* w_m1  = (const float*)d_in[15];
  const float* b_m1  = (const float*)d_in[16];
  const float* w_m2  = (const float*)d_in[17];
  const float* b_m2  = (const float*)d_in[18];
  const float* w_out = (const float*)d_in[19];
  const float* b_out = (const float*)d_in[20];
  const float* offp  = (const float*)d_in[21];

  char* ws = (char*)d_ws;
  auto carve = [&](size_t bytes){ char* p = ws; ws += (bytes + 255) & ~(size_t)255; return p; };
  float* h   = (float*)carve((size_t)NTOK * CDIM * 4);
  u16* a     = (u16*)carve((size_t)NTOK * CDIM * 2);
  u16* qkvb  = (u16*)carve((size_t)NTOK * QKVD * 2);
  u16* vT    = (u16*)carve((size_t)NTOK * CDIM * 2);
  u16* ob    = (u16*)carve((size_t)NTOK * CDIM * 2);
  u16* ub    = (u16*)carve((size_t)NTOK * MLPD * 2);
  u16* wqkvT = (u16*)carve((size_t)LAYERS * QKVD * CDIM * 2);
  u16* woT   = (u16*)carve((size_t)LAYERS * CDIM * CDIM * 2);
  u16* wm1T  = (u16*)carve((size_t)LAYERS * MLPD * CDIM * 2);
  u16* wm2T  = (u16*)carve((size_t)LAYERS * CDIM * MLPD * 2);
  u16* woutT = (u16*)carve((size_t)64 * CDIM * 2);

  kt_prologue<<<10248, 256, 0, stream>>>(w_qkv, w_o, w_m1, w_m2, w_out,
                                         wqkvT, woT, wm1T, wm2T, woutT,
                                         feats, coords, emb_x, emb_y, emb_z, w_in, b_in, h);

  for (int l = 0; l < LAYERS; ++l){
    kt_ln<<<NTOK/4, 256, 0, stream>>>(h, ln1_g + l*CDIM, ln1_b + l*CDIM, a, 1e-6f);
    kt_gemm<128,64,0><<<(NTOK/128)*(QKVD/64), 256, 0, stream>>>(
        a, wqkvT + (size_t)l*QKVD*CDIM, b_qkv + l*QKVD, qkvb, nullptr, vT, QKVD, CDIM);
    kt_attn<<<512, 256, 0, stream>>>(qkvb, vT, ob);
    kt_gemm<64,64,1><<<(NTOK/64)*(CDIM/64), 256, 0, stream>>>(
        ob, woT + (size_t)l*CDIM*CDIM, b_o + l*CDIM, nullptr, h, nullptr, CDIM, CDIM);
    kt_ln<<<NTOK/4, 256, 0, stream>>>(h, ln2_g + l*CDIM, ln2_b + l*CDIM, a, 1e-6f);
    kt_gemm<128,64,2><<<(NTOK/128)*(MLPD/64), 256, 0, stream>>>(
        a, wm1T + (size_t)l*MLPD*CDIM, b_m1 + l*MLPD, ub, nullptr, nullptr, MLPD, CDIM);
    kt_gemm<64,64,1><<<(NTOK/64)*(CDIM/64), 256, 0, stream>>>(
        ub, wm2T + (size_t)l*CDIM*MLPD, b_m2 + l*CDIM, nullptr, h, nullptr, CDIM, MLPD);
  }
  kt_final<<<64, 256, 0, stream>>>(h, woutT, b_out, coords, offp, (float*)d_out);
}

// Round 17
// 822.889 us; speedup vs baseline: 1.0292x; 1.0221x over previous
//
#include <hip/hip_runtime.h>
#include <stdint.h>

typedef unsigned short u16;
typedef short bf16x8 __attribute__((ext_vector_type(8)));
typedef float f32x4 __attribute__((ext_vector_type(4)));

#define NTOK 4096
#define CDIM 512
#define NHEAD 8
#define LAYERS 8
#define MLPD 2048
#define QKVD 1536

__device__ __forceinline__ u16 f2bf(float f){
  union { float f; unsigned u; } c; c.f = f;
  return (u16)((c.u + 0x7FFFu + ((c.u >> 16) & 1u)) >> 16);
}

__device__ __forceinline__ void llds16(const void* g, void* l){
  __builtin_amdgcn_global_load_lds((const __attribute__((address_space(1))) void*)g,
                                   (__attribute__((address_space(3))) void*)l, 16, 0, 0);
}

template<int N> __device__ __forceinline__ void wait_vmcnt(){
  if constexpr (N == 0) asm volatile("s_waitcnt vmcnt(0)" ::: "memory");
  else if constexpr (N == 2) asm volatile("s_waitcnt vmcnt(2)" ::: "memory");
  else if constexpr (N == 4) asm volatile("s_waitcnt vmcnt(4)" ::: "memory");
  else static_assert(N == 0 || N == 2 || N == 4, "unsupported vmcnt");
}

// ------- merged prologue: weight transpose+convert (tiled bf16) + token embed ----------
// Wt layout: [n/64][k/64][64][64]. blocks 0..6143 transpose, 6144..6151 w_out (guarded),
// 6152..10247 embed (one token each). 10248 blocks.
__global__ void kt_prologue(const float* __restrict__ wqkv, const float* __restrict__ wo,
                            const float* __restrict__ wm1, const float* __restrict__ wm2,
                            const float* __restrict__ wout,
                            u16* __restrict__ qkvT, u16* __restrict__ oT,
                            u16* __restrict__ m1T, u16* __restrict__ m2T,
                            u16* __restrict__ outT,
                            const float* __restrict__ feats, const int* __restrict__ coords,
                            const float* __restrict__ ex, const float* __restrict__ ey,
                            const float* __restrict__ ez, const float* __restrict__ w_in,
                            const float* __restrict__ b_in, float* __restrict__ h){
  __shared__ float tile[64][65];
  __shared__ float fs[8];
  __shared__ int ccx[3];
  int bid = blockIdx.x;
  int t = threadIdx.x;

  if (bid >= 6152){           // ---- embed segment ----
    int n = bid - 6152;
    if (t < 8) fs[t] = feats[n * 8 + t];
    if (t == 8) { ccx[0] = coords[n*4+1]; ccx[1] = coords[n*4+2]; ccx[2] = coords[n*4+3]; }
    __syncthreads();
    for (int c = t; c < CDIM; c += 256){
      float acc = b_in[c];
      #pragma unroll
      for (int i = 0; i < 8; i++) acc += fs[i] * w_in[i * CDIM + c];
      float pe;
      if (c < 170)      pe = ex[ccx[0] * 170 + c];
      else if (c < 340) pe = ey[ccx[1] * 170 + (c - 170)];
      else              pe = ez[ccx[2] * 172 + (c - 340)];
      h[(size_t)n * CDIM + c] = acc + pe;
    }
    return;
  }

  const float* W; u16* Wt; int K, N, k0, n0; bool guard = false;
  if (bid < 1536){            // qkv: 24 n-tiles x 8 k-tiles per layer
    int l = bid / 192, r = bid % 192;
    W = wqkv + (size_t)l * 512 * 1536; Wt = qkvT + (size_t)l * 512 * 1536;
    K = 512; N = 1536; n0 = (r % 24) * 64; k0 = (r / 24) * 64;
  } else if (bid < 2048){     // o: 8 x 8
    int b = bid - 1536; int l = b / 64, r = b % 64;
    W = wo + (size_t)l * 512 * 512; Wt = oT + (size_t)l * 512 * 512;
    K = 512; N = 512; n0 = (r % 8) * 64; k0 = (r / 8) * 64;
  } else if (bid < 4096){     // m1: 32 x 8
    int b = bid - 2048; int l = b / 256, r = b % 256;
    W = wm1 + (size_t)l * 512 * 2048; Wt = m1T + (size_t)l * 512 * 2048;
    K = 512; N = 2048; n0 = (r % 32) * 64; k0 = (r / 32) * 64;
  } else if (bid < 6144){     // m2: 8 x 32
    int b = bid - 4096; int l = b / 256, r = b % 256;
    W = wm2 + (size_t)l * 2048 * 512; Wt = m2T + (size_t)l * 2048 * 512;
    K = 2048; N = 512; n0 = (r % 8) * 64; k0 = (r / 8) * 64;
  } else {                    // w_out: 1 n-tile (56 guarded, pad 64) x 8 k-tiles
    int r = bid - 6144;
    W = wout; Wt = outT;
    K = 512; N = 56; n0 = 0; k0 = r * 64;
    guard = true;
  }
  int kr = t >> 4, cc = (t & 15) << 2;
  if (guard){
    #pragma unroll
    for (int j = 0; j < 4; j++)
      #pragma unroll
      for (int i = 0; i < 4; i++){
        int col = n0 + cc + i;
        tile[kr + j * 16][cc + i] = (col < N) ? W[(size_t)(k0 + kr + j * 16) * N + col] : 0.f;
      }
  } else {
    #pragma unroll
    for (int j = 0; j < 4; j++){
      float4 v = *(const float4*)&W[(size_t)(k0 + kr + j * 16) * N + n0 + cc];
      tile[kr + j * 16][cc + 0] = v.x;
      tile[kr + j * 16][cc + 1] = v.y;
      tile[kr + j * 16][cc + 2] = v.z;
      tile[kr + j * 16][cc + 3] = v.w;
    }
  }
  __syncthreads();
  size_t tbase = ((size_t)(n0 >> 6) * (K >> 6) + (k0 >> 6)) << 12;
  int nr = t >> 3, kc = (t & 7) << 3;
  #pragma unroll
  for (int s = 0; s < 2; s++){
    int n = nr + s * 32;
    uint4 p;
    p.x = (unsigned)f2bf(tile[kc + 0][n]) | ((unsigned)f2bf(tile[kc + 1][n]) << 16);
    p.y = (unsigned)f2bf(tile[kc + 2][n]) | ((unsigned)f2bf(tile[kc + 3][n]) << 16);
    p.z = (unsigned)f2bf(tile[kc + 4][n]) | ((unsigned)f2bf(tile[kc + 5][n]) << 16);
    p.w = (unsigned)f2bf(tile[kc + 6][n]) | ((unsigned)f2bf(tile[kc + 7][n]) << 16);
    *(uint4*)&Wt[tbase + (size_t)n * 64 + kc] = p;
  }
}

// ---------------- LayerNorm: fp32 h -> bf16 out ----------------
__global__ void kt_ln(const float* __restrict__ h, const float* __restrict__ g,
                      const float* __restrict__ b, u16* __restrict__ out, float eps){
  int wave = threadIdx.x >> 6, lane = threadIdx.x & 63;
  int row = blockIdx.x * 4 + wave;
  const float* hr = h + (size_t)row * CDIM + lane * 8;
  float4 v0 = *(const float4*)hr, v1 = *(const float4*)(hr + 4);
  float x[8] = {v0.x, v0.y, v0.z, v0.w, v1.x, v1.y, v1.z, v1.w};
  float s = 0.f, q = 0.f;
  #pragma unroll
  for (int i = 0; i < 8; i++){ s += x[i]; q += x[i] * x[i]; }
  #pragma unroll
  for (int off = 32; off; off >>= 1){ s += __shfl_xor(s, off); q += __shfl_xor(q, off); }
  float mean = s * (1.0f / CDIM);
  float var  = q * (1.0f / CDIM) - mean * mean;
  float rr = rsqrtf(var + eps);
  int cb = lane * 8;
  u16 u[8];
  #pragma unroll
  for (int i = 0; i < 8; i++)
    u[i] = f2bf((x[i] - mean) * rr * g[cb + i] + b[cb + i]);
  uint4 pk;
  pk.x = (unsigned)u[0] | ((unsigned)u[1] << 16);
  pk.y = (unsigned)u[2] | ((unsigned)u[3] << 16);
  pk.z = (unsigned)u[4] | ((unsigned)u[5] << 16);
  pk.w = (unsigned)u[6] | ((unsigned)u[7] << 16);
  *(uint4*)&out[(size_t)row * CDIM + cb] = pk;
}

// ---------------- bf16 GEMM: C[M=4096][N] = A[M][K] @ Wt(tiled)^T + bias ----------------
// A row-major; Wt tiled [n/64][k/64][64][64]. 2-buffer, one __syncthreads per K-step.
// 4 waves; wave tile (BM/2)x(BN/2). XCD-chunked 1D grid swizzle.
template<int BM, int BN, int MODE>
__global__ __launch_bounds__(256) void kt_gemm(
    const u16* __restrict__ A, const u16* __restrict__ Wt, const float* __restrict__ bias,
    u16* __restrict__ outb, float* __restrict__ hres, u16* __restrict__ vT, int N, int K)
{
  constexpr int MF = BM / 32;
  constexpr int NF = BN / 32;
  constexpr int Mt = NTOK / BM;
  constexpr int Mx = Mt / 8;
  __shared__ __align__(16) u16 As[2][BM * 64];
  __shared__ __align__(16) u16 Bs[2][BN * 64];
  int tid = threadIdx.x, wave = tid >> 6, lane = tid & 63;

  int Nt = N / BN;
  int bid = blockIdx.x;
  int xcd = bid & 7, slot = bid >> 3;
  int miL = slot / Nt;
  int ni = slot - miL * Nt;
  int m0 = (xcd * Mx + miL) * BM, n0 = ni * BN;

  int wm = wave >> 1, wn = wave & 1;
  f32x4 acc[MF][NF];
  const f32x4 fzero = {0.f, 0.f, 0.f, 0.f};
  #pragma unroll
  for (int m = 0; m < MF; m++)
    #pragma unroll
    for (int n = 0; n < NF; n++) acc[m][n] = fzero;

  int srow = lane >> 3;
  int sblk = (lane & 7) ^ srow;
  const u16* gA = A + (size_t)(m0 + wave * 8 + srow) * K + sblk * 8;
  int K64 = K >> 6;

  size_t btile[NF];
  int    bofs [NF];
  #pragma unroll
  for (int j = 0; j < NF; j++){
    int row = n0 + j * 32 + wave * 8 + srow;
    btile[j] = (size_t)(row >> 6) * K64;
    bofs[j]  = (row & 63) * 64 + sblk * 8;
  }

  auto stage = [&](int buf, int kt){
    #pragma unroll
    for (int j = 0; j < MF; j++)
      llds16(gA + (size_t)(j * 32) * K + kt, &As[buf][(j * 32 + wave * 8) * 64]);
    int ktile = kt >> 6;
    #pragma unroll
    for (int j = 0; j < NF; j++)
      llds16(Wt + ((btile[j] + ktile) << 12) + bofs[j], &Bs[buf][(j * 32 + wave * 8) * 64]);
  };

  int nk = K >> 6;
  stage(0, 0);
  __syncthreads();
  int rl = lane & 15, hg = lane >> 4;
  for (int t = 0; t < nk; ++t){
    int cur = t & 1;
    if (t + 1 < nk) stage(cur ^ 1, (t + 1) << 6);
    #pragma unroll
    for (int kk = 0; kk < 2; kk++){
      bf16x8 af[MF], bfr[NF];
      int bl = (kk << 2) + hg;
      #pragma unroll
      for (int m = 0; m < MF; m++){
        int row = wm * (BM / 2) + m * 16 + rl;
        af[m] = *(const bf16x8*)&As[cur][row * 64 + ((bl ^ (row & 7)) << 3)];
      }
      #pragma unroll
      for (int n = 0; n < NF; n++){
        int row = wn * (BN / 2) + n * 16 + rl;
        bfr[n] = *(const bf16x8*)&Bs[cur][row * 64 + ((bl ^ (row & 7)) << 3)];
      }
      #pragma unroll
      for (int m = 0; m < MF; m++)
        #pragma unroll
        for (int n = 0; n < NF; n++)
          acc[m][n] = __builtin_amdgcn_mfma_f32_16x16x32_bf16(af[m], bfr[n], acc[m][n], 0, 0, 0);
    }
    __syncthreads();
  }

  int cl = lane & 15, rg = lane >> 4;
  #pragma unroll
  for (int m = 0; m < MF; m++){
    int row0 = m0 + wm * (BM / 2) + m * 16 + rg * 4;
    #pragma unroll
    for (int n = 0; n < NF; n++){
      int col = n0 + wn * (BN / 2) + n * 16 + cl;
      float bb = bias[col];
      if (MODE == 1){
        #pragma unroll
        for (int r = 0; r < 4; r++){
          size_t idx = (size_t)(row0 + r) * N + col;
          hres[idx] += acc[m][n][r] + bb;
        }
      } else if (MODE == 2){
        #pragma unroll
        for (int r = 0; r < 4; r++){
          float x = acc[m][n][r] + bb;
          float t = 0.7978845608028654f * (x + 0.044715f * x * x * x);
          float sg = 1.0f / (1.0f + __expf(-2.0f * t));   // 0.5*(1+tanh(t)) == sigmoid(2t)
          outb[(size_t)(row0 + r) * N + col] = f2bf(x * sg);
        }
      } else {
        if (col < 1024){
          #pragma unroll
          for (int r = 0; r < 4; r++)
            outb[(size_t)(row0 + r) * N + col] = f2bf(acc[m][n][r] + bb);
        } else {
          int dh = col - 1024;
          int win = row0 >> 9, tin = row0 & 511;
          ushort4 p;
          p.x = f2bf(acc[m][n][0] + bb);
          p.y = f2bf(acc[m][n][1] + bb);
          p.z = f2bf(acc[m][n][2] + bb);
          p.w = f2bf(acc[m][n][3] + bb);
          *(ushort4*)&vT[(size_t)(win * 512 + dh) * 512 + tin] = p;
        }
      }
    }
  }
}

// ---------------- windowed flash attention: LDS-staged K/V (3-buf, counted vmcnt) -------
// 512 blocks x 4 waves. XCD-affinity remap: the 8 q8-blocks sharing one (win,head)'s
// 128KB K/V co-locate on one XCD (same mechanism as the GEMM swizzle, T1).
__global__ __launch_bounds__(256) void kt_attn(const u16* __restrict__ qkv,
                                               const u16* __restrict__ vT,
                                               u16* __restrict__ o){
  __shared__ __align__(16) u16 Ks[3][32 * 64];
  __shared__ __align__(16) u16 Vs[3][64 * 32];
  int tid = threadIdx.x, wave = tid >> 6, lane = tid & 63;
  int bx = blockIdx.x;
  int xcd = bx & 7, slot = bx >> 3;          // 64 slots per XCD
  int pair = xcd * 8 + (slot >> 3);          // (win,head) pair; 8 pairs per XCD
  int win = pair >> 3, head = pair & 7, q8 = slot & 7;
  int rl = lane & 15, hg = lane >> 4;
  int qbase = win * 512 + q8 * 64 + wave * 16;
  const u16* qptr  = qkv + (size_t)(qbase + rl) * QKVD + head * 64;
  const u16* kbase = qkv + (size_t)(win * 512) * QKVD + 512 + head * 64;
  const u16* vbase = vT + (size_t)(win * 512 + head * 64) * 512;

  int krow = tid >> 3;
  const u16* gK = kbase + (size_t)krow * QKVD + (((tid & 7) ^ (krow & 7)) << 3);
  int vrow = tid >> 2;
  const u16* gV = vbase + (size_t)vrow * 512 + (((tid & 3) ^ (vrow & 3)) << 3);

  auto stage = [&](int buf, int kt){
    llds16(gK + (size_t)kt * QKVD, &Ks[buf][tid * 8]);
    llds16(gV + kt, &Vs[buf][tid * 8]);
  };

  bf16x8 qf0 = *(const bf16x8*)(qptr + hg * 8);
  bf16x8 qf1 = *(const bf16x8*)(qptr + 32 + hg * 8);

  const f32x4 fzero = {0.f, 0.f, 0.f, 0.f};
  f32x4 Oa[4] = {fzero, fzero, fzero, fzero};
  float mrun = -1e30f, lrun = 0.f;

  stage(0, 0);
  stage(1, 32);
  for (int t = 0; t < 16; ++t){
    int cur = t % 3;
    if (t + 1 < 16) wait_vmcnt<2>(); else wait_vmcnt<0>();
    __builtin_amdgcn_s_barrier();
    asm volatile("" ::: "memory");
    if (t + 2 < 16) stage((t + 2) % 3, (t + 2) * 32);

    bf16x8 kf[2][2];
    #pragma unroll
    for (int c = 0; c < 2; c++)
      #pragma unroll
      for (int dk = 0; dk < 2; dk++){
        int row = c * 16 + rl;
        kf[c][dk] = *(const bf16x8*)&Ks[cur][row * 64 + ((((dk << 2) + hg) ^ (rl & 7)) << 3)];
      }
    bf16x8 vf[4];
    #pragma unroll
    for (int d = 0; d < 4; d++){
      int row = d * 16 + rl;
      vf[d] = *(const bf16x8*)&Vs[cur][row * 32 + ((hg ^ (rl & 3)) << 3)];
    }

    f32x4 s0 = fzero, s1 = fzero;
    s0 = __builtin_amdgcn_mfma_f32_16x16x32_bf16(kf[0][0], qf0, s0, 0, 0, 0);
    s0 = __builtin_amdgcn_mfma_f32_16x16x32_bf16(kf[0][1], qf1, s0, 0, 0, 0);
    s1 = __builtin_amdgcn_mfma_f32_16x16x32_bf16(kf[1][0], qf0, s1, 0, 0, 0);
    s1 = __builtin_amdgcn_mfma_f32_16x16x32_bf16(kf[1][1], qf1, s1, 0, 0, 0);
    float v[8];
    #pragma unroll
    for (int r = 0; r < 4; r++){ v[r] = s0[r] * 0.125f; v[4 + r] = s1[r] * 0.125f; }
    float tmax = v[0];
    #pragma unroll
    for (int i = 1; i < 8; i++) tmax = fmaxf(tmax, v[i]);
    tmax = fmaxf(tmax, __shfl_xor(tmax, 16));
    tmax = fmaxf(tmax, __shfl_xor(tmax, 32));
    float mnew = fmaxf(mrun, tmax);
    float corr = __expf(mrun - mnew);
    mrun = mnew;
    float p[8], ps = 0.f;
    #pragma unroll
    for (int i = 0; i < 8; i++){ p[i] = __expf(v[i] - mnew); ps += p[i]; }
    ps += __shfl_xor(ps, 16);
    ps += __shfl_xor(ps, 32);
    lrun = lrun * corr + ps;
    float c0 = __shfl(corr, (hg << 2) + 0);
    float c1 = __shfl(corr, (hg << 2) + 1);
    float c2 = __shfl(corr, (hg << 2) + 2);
    float c3 = __shfl(corr, (hg << 2) + 3);
    #pragma unroll
    for (int d = 0; d < 4; d++){
      Oa[d][0] *= c0; Oa[d][1] *= c1; Oa[d][2] *= c2; Oa[d][3] *= c3;
    }
    unsigned pk00 = (unsigned)f2bf(p[0]) | ((unsigned)f2bf(p[1]) << 16);
    unsigned pk01 = (unsigned)f2bf(p[2]) | ((unsigned)f2bf(p[3]) << 16);
    unsigned pk10 = (unsigned)f2bf(p[4]) | ((unsigned)f2bf(p[5]) << 16);
    unsigned pk11 = (unsigned)f2bf(p[6]) | ((unsigned)f2bf(p[7]) << 16);
    int idx0 = rl | ((( hg << 1)      & 3) << 4);
    int idx1 = rl | ((((hg << 1) + 1) & 3) << 4);
    bool hiC = hg >= 2;
    unsigned W0a = __shfl(pk00, idx0), W0b = __shfl(pk10, idx0);
    unsigned W1a = __shfl(pk01, idx0), W1b = __shfl(pk11, idx0);
    unsigned W2a = __shfl(pk00, idx1), W2b = __shfl(pk10, idx1);
    unsigned W3a = __shfl(pk01, idx1), W3b = __shfl(pk11, idx1);
    uint4 W;
    W.x = hiC ? W0b : W0a;
    W.y = hiC ? W1b : W1a;
    W.z = hiC ? W2b : W2a;
    W.w = hiC ? W3b : W3a;
    bf16x8 pf;
    __builtin_memcpy(&pf, &W, 16);
    #pragma unroll
    for (int d = 0; d < 4; d++)
      Oa[d] = __builtin_amdgcn_mfma_f32_16x16x32_bf16(pf, vf[d], Oa[d], 0, 0, 0);
  }

  float l0 = __shfl(lrun, (hg << 2) + 0);
  float l1 = __shfl(lrun, (hg << 2) + 1);
  float l2 = __shfl(lrun, (hg << 2) + 2);
  float l3 = __shfl(lrun, (hg << 2) + 3);
  float li[4] = {1.f / l0, 1.f / l1, 1.f / l2, 1.f / l3};
  #pragma unroll
  for (int d = 0; d < 4; d++)
    #pragma unroll
    for (int r = 0; r < 4; r++){
      int row = qbase + (hg << 2) + r;
      o[(size_t)row * CDIM + head * 64 + d * 16 + rl] = f2bf(Oa[d][r] * li[r]);
    }
}

// ------------- final: fused LN(eps 1e-5) + head GEMM (N=56 pad 64) + post-process -------
__global__ __launch_bounds__(256) void kt_final(const float* __restrict__ h,
                                                const u16* __restrict__ WoT,
                                                const float* __restrict__ b_out,
                                                const int* __restrict__ coords,
                                                const float* __restrict__ offp,
                                                float* __restrict__ out){
  __shared__ __align__(16) u16 As[2][64 * 64];
  __shared__ __align__(16) u16 Bs[2][64 * 64];
  __shared__ float Mu[64], Rs[64];
  int tid = threadIdx.x, wave = tid >> 6, lane = tid & 63;
  int m0 = blockIdx.x * 64;
  int wm = wave >> 1, wn = wave & 1;

  for (int rr = 0; rr < 16; ++rr){
    int rloc = wave * 16 + rr;
    const float* hp = h + (size_t)(m0 + rloc) * CDIM + lane * 8;
    float4 v0 = *(const float4*)hp, v1 = *(const float4*)(hp + 4);
    float x[8] = {v0.x, v0.y, v0.z, v0.w, v1.x, v1.y, v1.z, v1.w};
    float s = 0.f, q = 0.f;
    #pragma unroll
    for (int i = 0; i < 8; i++){ s += x[i]; q += x[i] * x[i]; }
    #pragma unroll
    for (int off = 32; off; off >>= 1){ s += __shfl_xor(s, off); q += __shfl_xor(q, off); }
    if (lane == 0){
      float mean = s * (1.0f / CDIM);
      float var  = q * (1.0f / CDIM) - mean * mean;
      Mu[rloc] = mean;
      Rs[rloc] = rsqrtf(var + 1e-5f);
    }
  }
  __syncthreads();

  int ar = tid >> 2, ac = tid & 3;
  float mu_ = Mu[ar], rs_ = Rs[ar];

  auto stageA = [&](int buf, int kt){
    const float* hp = h + (size_t)(m0 + ar) * CDIM + kt + ac * 16;
    float4 a0 = *(const float4*)hp, a1 = *(const float4*)(hp + 4);
    float4 a2 = *(const float4*)(hp + 8), a3 = *(const float4*)(hp + 12);
    float x[16] = {a0.x,a0.y,a0.z,a0.w, a1.x,a1.y,a1.z,a1.w,
                   a2.x,a2.y,a2.z,a2.w, a3.x,a3.y,a3.z,a3.w};
    u16 w[16];
    #pragma unroll
    for (int i = 0; i < 16; i++) w[i] = f2bf((x[i] - mu_) * rs_);
    uint4 p0, p1;
    p0.x = (unsigned)w[0] | ((unsigned)w[1] << 16);
    p0.y = (unsigned)w[2] | ((unsigned)w[3] << 16);
    p0.z = (unsigned)w[4] | ((unsigned)w[5] << 16);
    p0.w = (unsigned)w[6] | ((unsigned)w[7] << 16);
    p1.x = (unsigned)w[8] | ((unsigned)w[9] << 16);
    p1.y = (unsigned)w[10] | ((unsigned)w[11] << 16);
    p1.z = (unsigned)w[12] | ((unsigned)w[13] << 16);
    p1.w = (unsigned)w[14] | ((unsigned)w[15] << 16);
    int j0 = ac * 2, j1 = ac * 2 + 1;
    *(uint4*)&As[buf][ar * 64 + ((j0 ^ (ar & 7)) << 3)] = p0;
    *(uint4*)&As[buf][ar * 64 + ((j1 ^ (ar & 7)) << 3)] = p1;
  };

  int srow = lane >> 3;
  int sblk = (lane & 7) ^ srow;
  int bofs[2];
  #pragma unroll
  for (int j = 0; j < 2; j++)
    bofs[j] = (j * 32 + wave * 8 + srow) * 64 + sblk * 8;
  auto stageB = [&](int buf, int kt){
    int ktile = kt >> 6;
    #pragma unroll
    for (int j = 0; j < 2; j++)
      llds16(WoT + (ktile << 12) + bofs[j], &Bs[buf][(j * 32 + wave * 8) * 64]);
  };

  f32x4 acc[2][2];
  const f32x4 fzero = {0.f, 0.f, 0.f, 0.f};
  acc[0][0] = fzero; acc[0][1] = fzero; acc[1][0] = fzero; acc[1][1] = fzero;

  stageB(0, 0);
  stageA(0, 0);
  __syncthreads();
  int rl = lane & 15, hg = lane >> 4;
  for (int t = 0; t < 8; ++t){
    int cur = t & 1;
    if (t + 1 < 8){
      stageB(cur ^ 1, (t + 1) << 6);
      stageA(cur ^ 1, (t + 1) << 6);
    }
    #pragma unroll
    for (int kk = 0; kk < 2; kk++){
      bf16x8 af[2], bfr[2];
      int bl = (kk << 2) + hg;
      #pragma unroll
      for (int m = 0; m < 2; m++){
        int row = wm * 32 + m * 16 + rl;
        af[m] = *(const bf16x8*)&As[cur][row * 64 + ((bl ^ (row & 7)) << 3)];
      }
      #pragma unroll
      for (int n = 0; n < 2; n++){
        int row = wn * 32 + n * 16 + rl;
        bfr[n] = *(const bf16x8*)&Bs[cur][row * 64 + ((bl ^ (row & 7)) << 3)];
      }
      #pragma unroll
      for (int m = 0; m < 2; m++)
        #pragma unroll
        for (int n = 0; n < 2; n++)
          acc[m][n] = __builtin_amdgcn_mfma_f32_16x16x32_bf16(af[m], bfr[n], acc[m][n], 0, 0, 0);
    }
    __syncthreads();
  }

  int cl = lane & 15, rg = lane >> 4;
  #pragma unroll
  for (int m = 0; m < 2; m++){
    int row0 = m0 + wm * 32 + m * 16 + rg * 4;
    #pragma unroll
    for (int n = 0; n < 2; n++){
      int col = wn * 32 + n * 16 + cl;
      if (col < 56){
        float bb = b_out[col];
        #pragma unroll
        for (int r = 0; r < 4; r++){
          int row = row0 + r;
          float v = acc[m][n][r] + bb;
          if (col < 12){
            int d = col - (col / 3) * 3;
            float base = ((float)coords[row * 4 + 1 + d] + 0.5f) * (1.0f / 16.0f);
            float tt = tanhf(v + offp[col]);
            out[(size_t)row * 12 + col] = base + tt * 4.8828125e-4f;
          } else if (col < 24){
            out[49152 + (size_t)row * 12 + (col - 12)] = v;
          } else if (col < 36){
            out[98304 + (size_t)row * 12 + (col - 24)] = v;
          } else if (col < 52){
            out[147456 + (size_t)row * 16 + (col - 36)] = v;
          } else {
            out[212992 + (size_t)row * 4 + (col - 52)] = v;
          }
        }
      }
    }
  }
}

extern "C" void kernel_launch(void* const* d_in, const int* in_sizes, int n_in,
                              void* d_out, int out_size, void* d_ws, size_t ws_size,
                              hipStream_t stream) {
  const float* feats = (const float*)d_in[0];
  const int*   coords = (const int*)d_in[1];
  const float* emb_x = (const float*)d_in[2];
  const float* emb_y = (const float*)d_in[3];
  const float* emb_z = (const float*)d_in[4];
  const float* w_in  = (const float*)d_in[5];
  const float* b_in  = (const float*)d_in[6];
  const float* ln1_g = (const float*)d_in[7];
  const float* ln1_b = (const float*)d_in[8];
  const float* w_qkv = (const float*)d_in[9];
  const float* b_qkv = (const float*)d_in[10];
  const float* w_o   = (const float*)d_in[11];
  const float* b_o   = (const float*)d_in[12];
  const float* ln2_g = (const float*)d_in[13];
  const float* ln2_b = (const float*)d_in[14];
  const float* w_m1  = (const float*)d_in[15];
  const float* b_m1  = (const float*)d_in[16];
  const float* w_m2  = (const float*)d_in[17];
  const float* b_m2  = (const float*)d_in[18];
  const float* w_out = (const float*)d_in[19];
  const float* b_out = (const float*)d_in[20];
  const float* offp  = (const float*)d_in[21];

  char* ws = (char*)d_ws;
  auto carve = [&](size_t bytes){ char* p = ws; ws += (bytes + 255) & ~(size_t)255; return p; };
  float* h   = (float*)carve((size_t)NTOK * CDIM * 4);
  u16* a     = (u16*)carve((size_t)NTOK * CDIM * 2);
  u16* qkvb  = (u16*)carve((size_t)NTOK * QKVD * 2);
  u16* vT    = (u16*)carve((size_t)NTOK * CDIM * 2);
  u16* ob    = (u16*)carve((size_t)NTOK * CDIM * 2);
  u16* ub    = (u16*)carve((size_t)NTOK * MLPD * 2);
  u16* wqkvT = (u16*)carve((size_t)LAYERS * QKVD * CDIM * 2);
  u16* woT   = (u16*)carve((size_t)LAYERS * CDIM * CDIM * 2);
  u16* wm1T  = (u16*)carve((size_t)LAYERS * MLPD * CDIM * 2);
  u16* wm2T  = (u16*)carve((size_t)LAYERS * CDIM * MLPD * 2);
  u16* woutT = (u16*)carve((size_t)64 * CDIM * 2);

  kt_prologue<<<10248, 256, 0, stream>>>(w_qkv, w_o, w_m1, w_m2, w_out,
                                         wqkvT, woT, wm1T, wm2T, woutT,
                                         feats, coords, emb_x, emb_y, emb_z, w_in, b_in, h);

  for (int l = 0; l < LAYERS; ++l){
    kt_ln<<<NTOK/4, 256, 0, stream>>>(h, ln1_g + l*CDIM, ln1_b + l*CDIM, a, 1e-6f);
    kt_gemm<128,64,0><<<(NTOK/128)*(QKVD/64), 256, 0, stream>>>(
        a, wqkvT + (size_t)l*QKVD*CDIM, b_qkv + l*QKVD, qkvb, nullptr, vT, QKVD, CDIM);
    kt_attn<<<512, 256, 0, stream>>>(qkvb, vT, ob);
    kt_gemm<64,64,1><<<(NTOK/64)*(CDIM/64), 256, 0, stream>>>(
        ob, woT + (size_t)l*CDIM*CDIM, b_o + l*CDIM, nullptr, h, nullptr, CDIM, CDIM);
    kt_ln<<<NTOK/4, 256, 0, stream>>>(h, ln2_g + l*CDIM, ln2_b + l*CDIM, a, 1e-6f);
    kt_gemm<128,64,2><<<(NTOK/128)*(MLPD/64), 256, 0, stream>>>(
        a, wm1T + (size_t)l*MLPD*CDIM, b_m1 + l*MLPD, ub, nullptr, nullptr, MLPD, CDIM);
    kt_gemm<64,64,1><<<(NTOK/64)*(CDIM/64), 256, 0, stream>>>(
        ub, wm2T + (size_t)l*CDIM*MLPD, b_m2 + l*CDIM, nullptr, h, nullptr, CDIM, MLPD);
  }
  kt_final<<<64, 256, 0, stream>>>(h, woutT, b_out, coords, offp, (float*)d_out);
}